// Round 4
// baseline (330.410 us; speedup 1.0000x reference)
//
#include <hip/hip_runtime.h>

// PNN fused, round 4: two-kernel pipeline.
//
// Kernel 1 (pnn_stage): gather + scale + f16-convert the embedding matrix
//   A[16384 x 624] into d_ws, pre-swizzled in MFMA A-fragment order:
//   Aws[rowtile(1024)][kstep(20)][lane(64)][8 halfs], K padded 624->640 with
//   zeros. Assembled per-rowtile in LDS, flushed fully coalesced.
//   20 extra blocks convert w_first||w_inner into B-fragment order:
//   Wws[coltile(4)][kstep(20)][lane(64)][8 halfs].
//
// Kernel 2 (pnn_gemm): C[32x64] per block = A x Wcat via
//   mfma_f32_16x16x32_f16; K-loop = 2 coalesced dwordx4 + 1 MFMA per step.
//   Then the round-3-verified fused MLP epilogue (fp32, LDS).

namespace {

typedef _Float16 half8 __attribute__((ext_vector_type(8)));
typedef float floatx4 __attribute__((ext_vector_type(4)));

constexpr int Bn = 16384;
constexpr int Fn = 39;
constexpr int Vn = 100000;
constexpr int En = 16;
constexpr int M = 32;                 // rows per gemm block
constexpr int KST = 20;               // k-steps of 32 (624 padded to 640)
constexpr int NRT = Bn / 16;          // 1024 rowtiles of 16
constexpr int WBLOCKS = 20;           // weight-conversion blocks (5120 slots)
constexpr int AWS_OFF_H = 65536;      // Aws offset in halfs (byte 131072)

__device__ __forceinline__ half8 cvt8s(float4 a, float4 b, float s) {
    half8 h;
    h[0] = (_Float16)(a.x * s); h[1] = (_Float16)(a.y * s);
    h[2] = (_Float16)(a.z * s); h[3] = (_Float16)(a.w * s);
    h[4] = (_Float16)(b.x * s); h[5] = (_Float16)(b.y * s);
    h[6] = (_Float16)(b.z * s); h[7] = (_Float16)(b.w * s);
    return h;
}

__device__ __forceinline__ half8 cvt8(float4 a, float4 b) {
    half8 h;
    h[0] = (_Float16)a.x; h[1] = (_Float16)a.y;
    h[2] = (_Float16)a.z; h[3] = (_Float16)a.w;
    h[4] = (_Float16)b.x; h[5] = (_Float16)b.y;
    h[6] = (_Float16)b.z; h[7] = (_Float16)b.w;
    return h;
}

// ---------------- Kernel 1: stage A (gather) + stage W ----------------
__global__ __launch_bounds__(256) void pnn_stage(
    const int* __restrict__ Xi,
    const float* __restrict__ Xv,
    const float* __restrict__ T,
    const float* __restrict__ w_first,
    const float* __restrict__ w_inner,
    _Float16* __restrict__ ws)
{
    _Float16* __restrict__ Wws = ws;               // 5120*8 halfs = 80 KB
    _Float16* __restrict__ Aws = ws + AWS_OFF_H;   // 1024*20*512 halfs = 21 MB

    const int tid = threadIdx.x;

    if (blockIdx.x >= NRT) {
        // ---- weight conversion: one lane-slot (8 halfs) per thread ----
        const int slot = (blockIdx.x - NRT) * 256 + tid;        // 0..5119
        const int t16 = slot / (KST * 64);
        const int rem = slot % (KST * 64);
        const int t = rem >> 6;
        const int lane = rem & 63;
        const int n = t16 * 16 + (lane & 15);
        const int kb = t * 32 + (lane >> 4) * 8;
        half8 h = {0, 0, 0, 0, 0, 0, 0, 0};
        if (!(t == KST - 1 && (lane >> 4) >= 2)) {   // kb<=616 -> fully valid
            const float* src = ((n < 32) ? (w_first + (size_t)n * 624)
                                         : (w_inner + (size_t)(n - 32) * 624)) + kb;
            const float4 a = *reinterpret_cast<const float4*>(src);
            const float4 b = *reinterpret_cast<const float4*>(src + 4);
            h = cvt8(a, b);
        }
        *reinterpret_cast<half8*>(Wws + (size_t)slot * 8) = h;
        return;
    }

    // ---- gather one rowtile (16 rows x 39 features) ----
    __shared__ _Float16 At[KST * 512];   // 10240 halfs = 20 KB
    __shared__ int   xi[624];
    __shared__ float xv[624];

    const int rt = blockIdx.x;
    const int r0 = rt * 16;

    if (tid < 156) {   // 624/4 coalesced 16B stages
        reinterpret_cast<int4*>(xi)[tid] =
            reinterpret_cast<const int4*>(Xi + (size_t)r0 * Fn)[tid];
        reinterpret_cast<float4*>(xv)[tid] =
            reinterpret_cast<const float4*>(Xv + (size_t)r0 * Fn)[tid];
    }
    if (tid < 32) {    // zero K-pad: kstep 19, lanes 32..63
        half8 z = {0, 0, 0, 0, 0, 0, 0, 0};
        *reinterpret_cast<half8*>(At + ((KST - 1) * 64 + 32 + tid) * 8) = z;
    }
    __syncthreads();

    for (int i = tid; i < 624; i += 256) {
        const int r = i & 15, f = i >> 4;
        const int idx = xi[r * Fn + f];
        const float s = xv[r * Fn + f];
        const float4* src = reinterpret_cast<const float4*>(
            T + ((size_t)f * Vn + (size_t)idx) * En);
        const float4 q0 = src[0], q1 = src[1], q2 = src[2], q3 = src[3];
        // fragment slot: kstep t=f>>1, lane-groups (f&1)*2 and (f&1)*2+1, m=r
        const int base = (((f >> 1) * 64) + (f & 1) * 32 + r) * 8;
        *reinterpret_cast<half8*>(At + base)       = cvt8s(q0, q1, s);
        *reinterpret_cast<half8*>(At + base + 128) = cvt8s(q2, q3, s);
    }
    __syncthreads();

    // ---- flush 20 KB coalesced ----
    const int4* s4 = reinterpret_cast<const int4*>(At);
    int4* d4 = reinterpret_cast<int4*>(Aws + (size_t)rt * KST * 512);
#pragma unroll
    for (int j = 0; j < 5; ++j) d4[tid + j * 256] = s4[tid + j * 256];
}

// ---------------- Kernel 2: GEMM + fused MLP ----------------
struct SMemE {
    float x[M * 69];     // x[row][d], stride 69 -> conflict-free
    float wsh[2176];     // lin1_W[0..1023] lin2_W[1024..2047] b1@2048 b2@2080 lastW@2112 lastb@2144
    float r1[1024];
    float r2[1024];
};

__global__ __launch_bounds__(512) void pnn_gemm(
    const _Float16* __restrict__ ws,
    const float* __restrict__ lin1_W,
    const float* __restrict__ lin1_b,
    const float* __restrict__ lin2_W,
    const float* __restrict__ lin2_b,
    const float* __restrict__ last_W,
    const float* __restrict__ last_b,
    float* __restrict__ out)
{
    __shared__ SMemE sm;

    const _Float16* __restrict__ Wws = ws;
    const _Float16* __restrict__ Aws = ws + AWS_OFF_H;

    const int tid = threadIdx.x;
    const int lane = tid & 63;
    const int wv = tid >> 6;
    const int q = wv & 1;        // row-half (16 rows)
    const int t16 = wv >> 1;     // col-tile (16 cols)
    const int row0 = blockIdx.x * M;

    const _Float16* aptr = Aws + ((size_t)(blockIdx.x * 2 + q) * KST) * 512 + lane * 8;
    const _Float16* bptr = Wws + ((size_t)t16 * KST) * 512 + lane * 8;

    floatx4 acc = {0.0f, 0.0f, 0.0f, 0.0f};
#pragma unroll
    for (int t = 0; t < KST; ++t) {
        const half8 af = *reinterpret_cast<const half8*>(aptr + t * 512);
        const half8 bf = *reinterpret_cast<const half8*>(bptr + t * 512);
        acc = __builtin_amdgcn_mfma_f32_16x16x32_f16(af, bf, acc, 0, 0, 0);
    }

    // ---- write C tile: col=lane&15, row=(lane>>4)*4+reg ----
    {
        const int col = t16 * 16 + (lane & 15);
        const int rbase = q * 16 + (lane >> 4) * 4;
#pragma unroll
        for (int r = 0; r < 4; ++r)
            sm.x[(rbase + r) * 69 + col] = acc[r];
    }

    // ---- stage MLP weights ----
    for (int i = tid; i < 2145; i += 512) {
        float v;
        if (i < 1024)      v = lin1_W[i];
        else if (i < 2048) v = lin2_W[i - 1024];
        else if (i < 2080) v = lin1_b[i - 2048];
        else if (i < 2112) v = lin2_b[i - 2080];
        else if (i < 2144) v = last_W[i - 2112];
        else               v = last_b[0];
        sm.wsh[i] = v;
    }
    __syncthreads();

    // ---- xin[j][r] = first + s^2 ----
    for (int p = tid; p < 1024; p += 512) {
        const int j = p >> 5, r = p & 31;
        const float fi = sm.x[r * 69 + j];
        const float s  = sm.x[r * 69 + 32 + j];
        sm.r1[j * 32 + r] = fi + s * s;
    }
    __syncthreads();

    // ---- layer 1 ----
    {
        const int r = tid & 31, n0 = (tid >> 5) * 2;
        float a0 = sm.wsh[2048 + n0];
        float a1 = sm.wsh[2048 + n0 + 1];
#pragma unroll
        for (int j = 0; j < 32; ++j) {
            const float xj = sm.r1[j * 32 + r];
            a0 = fmaf(sm.wsh[n0 * 32 + j],       xj, a0);
            a1 = fmaf(sm.wsh[(n0 + 1) * 32 + j], xj, a1);
        }
        sm.r2[n0 * 32 + r]       = fmaxf(a0, 0.0f);
        sm.r2[(n0 + 1) * 32 + r] = fmaxf(a1, 0.0f);
    }
    __syncthreads();

    // ---- layer 2 ----
    {
        const int r = tid & 31, n0 = (tid >> 5) * 2;
        float a0 = sm.wsh[2080 + n0];
        float a1 = sm.wsh[2080 + n0 + 1];
#pragma unroll
        for (int j = 0; j < 32; ++j) {
            const float xj = sm.r2[j * 32 + r];
            a0 = fmaf(sm.wsh[1024 + n0 * 32 + j],       xj, a0);
            a1 = fmaf(sm.wsh[1024 + (n0 + 1) * 32 + j], xj, a1);
        }
        sm.r1[n0 * 32 + r]       = fmaxf(a0, 0.0f);
        sm.r1[(n0 + 1) * 32 + r] = fmaxf(a1, 0.0f);
    }
    __syncthreads();

    // ---- last layer + store ----
    if (tid < M) {
        float res = sm.wsh[2144];
#pragma unroll
        for (int j = 0; j < 32; ++j)
            res = fmaf(sm.wsh[2112 + j], sm.r1[j * 32 + tid], res);
        out[row0 + tid] = res;
    }
}

} // namespace

extern "C" void kernel_launch(void* const* d_in, const int* in_sizes, int n_in,
                              void* d_out, int out_size, void* d_ws, size_t ws_size,
                              hipStream_t stream) {
    (void)in_sizes; (void)n_in; (void)out_size; (void)ws_size;
    const int*   Xi      = (const int*)d_in[0];
    const float* Xv      = (const float*)d_in[1];
    const float* T       = (const float*)d_in[2];
    const float* w_first = (const float*)d_in[3];
    const float* w_inner = (const float*)d_in[4];
    const float* lin1_W  = (const float*)d_in[5];
    const float* lin1_b  = (const float*)d_in[6];
    const float* lin2_W  = (const float*)d_in[7];
    const float* lin2_b  = (const float*)d_in[8];
    const float* last_W  = (const float*)d_in[9];
    const float* last_b  = (const float*)d_in[10];
    float* out = (float*)d_out;
    _Float16* ws = (_Float16*)d_ws;

    hipLaunchKernelGGL(pnn_stage, dim3(NRT + WBLOCKS), dim3(256), 0, stream,
                       Xi, Xv, T, w_first, w_inner, ws);
    hipLaunchKernelGGL(pnn_gemm, dim3(Bn / M), dim3(512), 0, stream,
                       ws, lin1_W, lin1_b, lin2_W, lin2_b, last_W, last_b, out);
}

// Round 5
// 323.709 us; speedup vs baseline: 1.0207x; 1.0207x over previous
//
#include <hip/hip_runtime.h>

// PNN fused, round 5: two-kernel pipeline, gather de-divergence.
//
// Kernel 1 (pnn_stage), gather blocks: one rowtile (16 rows x 39 f = 624
//   random 64B lines) per block. NEW mapping: 4 consecutive lanes load the 4
//   x 16B chunks of one row -> each wave VMEM instr touches 16 lines (4-lane
//   coalesced), not 64; ~10 independent loads batched per thread before any
//   LDS write. Table loads nontemporal (reuse ~1.08, don't pollute L2).
//   Output: Aws[rowtile][kstep(20)][lane(64)][8 halfs], K zero-padded to 640,
//   flushed coalesced. 20 extra blocks convert weights to B-fragment order
//   (unchanged from round 4, verified).
//
// Kernel 2 (pnn_gemm): unchanged from round 4 (verified): K-loop = 2
//   coalesced dwordx4 + mfma_f32_16x16x32_f16, then fused fp32 MLP in LDS.

namespace {

typedef _Float16 half8 __attribute__((ext_vector_type(8)));
typedef _Float16 half4 __attribute__((ext_vector_type(4)));
typedef float floatx4 __attribute__((ext_vector_type(4)));
typedef float f32x4 __attribute__((ext_vector_type(4)));

constexpr int Bn = 16384;
constexpr int Fn = 39;
constexpr int Vn = 100000;
constexpr int En = 16;
constexpr int M = 32;                 // rows per gemm block
constexpr int KST = 20;               // k-steps of 32 (624 padded to 640)
constexpr int NRT = Bn / 16;          // 1024 rowtiles of 16
constexpr int WBLOCKS = 20;           // weight-conversion blocks (5120 slots)
constexpr int AWS_OFF_H = 65536;      // Aws offset in halfs (byte 131072)
constexpr int GITER = 10;             // ceil(2496 / 256) gather chunk-iters

__device__ __forceinline__ half8 cvt8(float4 a, float4 b) {
    half8 h;
    h[0] = (_Float16)a.x; h[1] = (_Float16)a.y;
    h[2] = (_Float16)a.z; h[3] = (_Float16)a.w;
    h[4] = (_Float16)b.x; h[5] = (_Float16)b.y;
    h[6] = (_Float16)b.z; h[7] = (_Float16)b.w;
    return h;
}

__device__ __forceinline__ half4 cvt4s(f32x4 a, float s) {
    half4 h;
    h[0] = (_Float16)(a[0] * s);
    h[1] = (_Float16)(a[1] * s);
    h[2] = (_Float16)(a[2] * s);
    h[3] = (_Float16)(a[3] * s);
    return h;
}

// ---------------- Kernel 1: stage A (gather) + stage W ----------------
__global__ __launch_bounds__(256) void pnn_stage(
    const int* __restrict__ Xi,
    const float* __restrict__ Xv,
    const float* __restrict__ T,
    const float* __restrict__ w_first,
    const float* __restrict__ w_inner,
    _Float16* __restrict__ ws)
{
    _Float16* __restrict__ Wws = ws;               // 5120*8 halfs = 80 KB
    _Float16* __restrict__ Aws = ws + AWS_OFF_H;   // 1024*20*512 halfs = 21 MB

    const int tid = threadIdx.x;

    if (blockIdx.x >= NRT) {
        // ---- weight conversion (verified round 4) ----
        const int slot = (blockIdx.x - NRT) * 256 + tid;        // 0..5119
        const int t16 = slot / (KST * 64);
        const int rem = slot % (KST * 64);
        const int t = rem >> 6;
        const int lane = rem & 63;
        const int n = t16 * 16 + (lane & 15);
        const int kb = t * 32 + (lane >> 4) * 8;
        half8 h = {0, 0, 0, 0, 0, 0, 0, 0};
        if (!(t == KST - 1 && (lane >> 4) >= 2)) {   // kb<=616 -> fully valid
            const float* src = ((n < 32) ? (w_first + (size_t)n * 624)
                                         : (w_inner + (size_t)(n - 32) * 624)) + kb;
            const float4 a = *reinterpret_cast<const float4*>(src);
            const float4 b = *reinterpret_cast<const float4*>(src + 4);
            h = cvt8(a, b);
        }
        *reinterpret_cast<half8*>(Wws + (size_t)slot * 8) = h;
        return;
    }

    // ---- gather one rowtile (16 rows x 39 features = 624 lines) ----
    __shared__ _Float16 At[KST * 512];   // 10240 halfs = 20 KB
    __shared__ int   xi[624];
    __shared__ float xv[624];

    const int rt = blockIdx.x;
    const int r0 = rt * 16;

    if (tid < 156) {   // coalesced 16B stages of Xi/Xv
        reinterpret_cast<int4*>(xi)[tid] =
            reinterpret_cast<const int4*>(Xi + (size_t)r0 * Fn)[tid];
        reinterpret_cast<float4*>(xv)[tid] =
            reinterpret_cast<const float4*>(Xv + (size_t)r0 * Fn)[tid];
    }
    if (tid < 32) {    // zero K-pad: kstep 19, lanes 32..63
        half8 z = {0, 0, 0, 0, 0, 0, 0, 0};
        *reinterpret_cast<half8*>(At + ((KST - 1) * 64 + 32 + tid) * 8) = z;
    }
    __syncthreads();

    // task i (0..2495): line j = i>>2 (row r=j&15, feature f=j>>4), chunk c=i&3.
    // 4 consecutive lanes share one 64B line -> wave instr = 16 lines,
    // 4-lane coalescable. All GITER loads issued before any LDS write.
    f32x4 v[GITER];
    float s[GITER];
    int   slot[GITER];
    bool  ok[GITER];
#pragma unroll
    for (int it = 0; it < GITER; ++it) {
        const int i = tid + it * 256;
        ok[it] = (i < 16 * Fn * 4);
        if (ok[it]) {
            const int j = i >> 2, c = i & 3;
            const int r = j & 15, f = j >> 4;
            const int idx = xi[r * Fn + f];
            s[it] = xv[r * Fn + f];
            const f32x4* src = reinterpret_cast<const f32x4*>(
                T + ((size_t)f * Vn + (size_t)idx) * En + c * 4);
            v[it] = __builtin_nontemporal_load(src);
            // frag slot (halfs): base=((f>>1)*64+(f&1)*32+r)*8, chunk offset
            slot[it] = (((f >> 1) * 64) + (f & 1) * 32 + r) * 8
                       + (c >> 1) * 128 + (c & 1) * 4;
        }
    }
#pragma unroll
    for (int it = 0; it < GITER; ++it) {
        if (ok[it])
            *reinterpret_cast<half4*>(At + slot[it]) = cvt4s(v[it], s[it]);
    }
    __syncthreads();

    // ---- flush 20 KB coalesced ----
    const int4* s4 = reinterpret_cast<const int4*>(At);
    int4* d4 = reinterpret_cast<int4*>(Aws + (size_t)rt * KST * 512);
#pragma unroll
    for (int j = 0; j < 5; ++j) d4[tid + j * 256] = s4[tid + j * 256];
}

// ---------------- Kernel 2: GEMM + fused MLP (verified round 4) ----------------
struct SMemE {
    float x[M * 69];     // x[row][d], stride 69 -> conflict-free
    float wsh[2176];     // lin1_W[0..1023] lin2_W[1024..2047] b1@2048 b2@2080 lastW@2112 lastb@2144
    float r1[1024];
    float r2[1024];
};

__global__ __launch_bounds__(512) void pnn_gemm(
    const _Float16* __restrict__ ws,
    const float* __restrict__ lin1_W,
    const float* __restrict__ lin1_b,
    const float* __restrict__ lin2_W,
    const float* __restrict__ lin2_b,
    const float* __restrict__ last_W,
    const float* __restrict__ last_b,
    float* __restrict__ out)
{
    __shared__ SMemE sm;

    const _Float16* __restrict__ Wws = ws;
    const _Float16* __restrict__ Aws = ws + AWS_OFF_H;

    const int tid = threadIdx.x;
    const int lane = tid & 63;
    const int wv = tid >> 6;
    const int q = wv & 1;        // row-half (16 rows)
    const int t16 = wv >> 1;     // col-tile (16 cols)
    const int row0 = blockIdx.x * M;

    const _Float16* aptr = Aws + ((size_t)(blockIdx.x * 2 + q) * KST) * 512 + lane * 8;
    const _Float16* bptr = Wws + ((size_t)t16 * KST) * 512 + lane * 8;

    floatx4 acc = {0.0f, 0.0f, 0.0f, 0.0f};
#pragma unroll
    for (int t = 0; t < KST; ++t) {
        const half8 af = *reinterpret_cast<const half8*>(aptr + t * 512);
        const half8 bf = *reinterpret_cast<const half8*>(bptr + t * 512);
        acc = __builtin_amdgcn_mfma_f32_16x16x32_f16(af, bf, acc, 0, 0, 0);
    }

    // ---- write C tile: col=lane&15, row=(lane>>4)*4+reg ----
    {
        const int col = t16 * 16 + (lane & 15);
        const int rbase = q * 16 + (lane >> 4) * 4;
#pragma unroll
        for (int r = 0; r < 4; ++r)
            sm.x[(rbase + r) * 69 + col] = acc[r];
    }

    // ---- stage MLP weights ----
    for (int i = tid; i < 2145; i += 512) {
        float v;
        if (i < 1024)      v = lin1_W[i];
        else if (i < 2048) v = lin2_W[i - 1024];
        else if (i < 2080) v = lin1_b[i - 2048];
        else if (i < 2112) v = lin2_b[i - 2080];
        else if (i < 2144) v = last_W[i - 2112];
        else               v = last_b[0];
        sm.wsh[i] = v;
    }
    __syncthreads();

    // ---- xin[j][r] = first + s^2 ----
    for (int p = tid; p < 1024; p += 512) {
        const int j = p >> 5, r = p & 31;
        const float fi = sm.x[r * 69 + j];
        const float sq = sm.x[r * 69 + 32 + j];
        sm.r1[j * 32 + r] = fi + sq * sq;
    }
    __syncthreads();

    // ---- layer 1 ----
    {
        const int r = tid & 31, n0 = (tid >> 5) * 2;
        float a0 = sm.wsh[2048 + n0];
        float a1 = sm.wsh[2048 + n0 + 1];
#pragma unroll
        for (int j = 0; j < 32; ++j) {
            const float xj = sm.r1[j * 32 + r];
            a0 = fmaf(sm.wsh[n0 * 32 + j],       xj, a0);
            a1 = fmaf(sm.wsh[(n0 + 1) * 32 + j], xj, a1);
        }
        sm.r2[n0 * 32 + r]       = fmaxf(a0, 0.0f);
        sm.r2[(n0 + 1) * 32 + r] = fmaxf(a1, 0.0f);
    }
    __syncthreads();

    // ---- layer 2 ----
    {
        const int r = tid & 31, n0 = (tid >> 5) * 2;
        float a0 = sm.wsh[2080 + n0];
        float a1 = sm.wsh[2080 + n0 + 1];
#pragma unroll
        for (int j = 0; j < 32; ++j) {
            const float xj = sm.r2[j * 32 + r];
            a0 = fmaf(sm.wsh[1024 + n0 * 32 + j],       xj, a0);
            a1 = fmaf(sm.wsh[1024 + (n0 + 1) * 32 + j], xj, a1);
        }
        sm.r1[n0 * 32 + r]       = fmaxf(a0, 0.0f);
        sm.r1[(n0 + 1) * 32 + r] = fmaxf(a1, 0.0f);
    }
    __syncthreads();

    // ---- last layer + store ----
    if (tid < M) {
        float res = sm.wsh[2144];
#pragma unroll
        for (int j = 0; j < 32; ++j)
            res = fmaf(sm.wsh[2112 + j], sm.r1[j * 32 + tid], res);
        out[row0 + tid] = res;
    }
}

} // namespace

extern "C" void kernel_launch(void* const* d_in, const int* in_sizes, int n_in,
                              void* d_out, int out_size, void* d_ws, size_t ws_size,
                              hipStream_t stream) {
    (void)in_sizes; (void)n_in; (void)out_size; (void)ws_size;
    const int*   Xi      = (const int*)d_in[0];
    const float* Xv      = (const float*)d_in[1];
    const float* T       = (const float*)d_in[2];
    const float* w_first = (const float*)d_in[3];
    const float* w_inner = (const float*)d_in[4];
    const float* lin1_W  = (const float*)d_in[5];
    const float* lin1_b  = (const float*)d_in[6];
    const float* lin2_W  = (const float*)d_in[7];
    const float* lin2_b  = (const float*)d_in[8];
    const float* last_W  = (const float*)d_in[9];
    const float* last_b  = (const float*)d_in[10];
    float* out = (float*)d_out;
    _Float16* ws = (_Float16*)d_ws;

    hipLaunchKernelGGL(pnn_stage, dim3(NRT + WBLOCKS), dim3(256), 0, stream,
                       Xi, Xv, T, w_first, w_inner, ws);
    hipLaunchKernelGGL(pnn_gemm, dim3(Bn / M), dim3(512), 0, stream,
                       ws, lin1_W, lin1_b, lin2_W, lin2_b, last_W, last_b, out);
}